// Round 13
// baseline (388.725 us; speedup 1.0000x reference)
//
#include <hip/hip_runtime.h>
#include <hip/hip_bf16.h>

typedef __attribute__((ext_vector_type(8))) short short8;
typedef __attribute__((ext_vector_type(4))) float floatx4;
typedef unsigned short u16;

#define D 256
#define BM 32
#define NT 128

__device__ __forceinline__ short f2bf(float f) {
    return __builtin_bit_cast(short, __float2bfloat16(f));
}

// prep: blocks [0,256): W1 fp32 [k][n] -> W1F bf16 MFMA-fragment-major:
// W1F[((k0t*16+nt)*64+lane)*8+j] = W1[k0t*32+(lane>>4)*8+j][nt*16+(lane&15)]
//       blocks [256,384): zero d_out.
__global__ void prep_kernel(const float* __restrict__ W1, u16* __restrict__ W1F,
                            float* __restrict__ out, int outn) {
    const int b = blockIdx.x;
    if (b < D) {
        const int k = b, n = threadIdx.x;
        const int k0t = k >> 5, g = (k >> 3) & 3, j = k & 7;
        const int nt = n >> 4, l15 = n & 15;
        W1F[(long)((((k0t << 4) + nt) << 6) + (g << 4) + l15) * 8 + j] = (u16)f2bf(W1[k * D + n]);
    } else {
        int i = (b - D) * 256 + threadIdx.x;
        const int stride = (gridDim.x - D) * 256;
        for (; i < outn; i += stride) out[i] = 0.f;
    }
}

// Max-TLP head: 32-edge tile, 2 waves, 16 KiB LDS -> 8 blocks/CU, 16 waves/CU.
// ONE barrier per block. Each wave owns 16 rows x 256 cols (16 col-frags), so
// the per-row reduce completes inside the wave (shfl over 16 lanes) and lane
// l15==0 scatters directly -- no cross-wave LDS reduce. forces is streamed
// with nontemporal loads (zero reuse); W1F/b1/W2 stay cached.
__launch_bounds__(NT, 4)
__global__ void head_kernel(const float* __restrict__ forces,
                            const float* __restrict__ V_st,
                            const u16*   __restrict__ W1F,
                            const float* __restrict__ b1,
                            const float* __restrict__ W2,
                            const float* __restrict__ b2,
                            const int*   __restrict__ idx_t,
                            float* __restrict__ out,
                            int E) {
    // frag f = k0t*2 + (row>>4); in-frag slot ((k>>3)*16 + (row&15))*8 + (k&7)
    __shared__ u16 Albs[16 * 512];    // 16 KiB

    const int tid  = threadIdx.x;
    const int lane = tid & 63;
    const int wm   = tid >> 6;        // 0..1: which 16-row half
    const int l15  = lane & 15;
    const int g    = lane >> 4;       // 0..3

    const long row0 = (long)blockIdx.x * BM;   // E%32==0: no tail

    // ---- scatter-operand prefetch, directly into the scattering lanes ----
    float vx[4], vy[4], vz[4];
    int nd[4];
    if (l15 == 0) {
#pragma unroll
        for (int rr = 0; rr < 4; ++rr) {
            long e = row0 + wm * 16 + g * 4 + rr;
            vx[rr] = V_st[e * 3 + 0];
            vy[rr] = V_st[e * 3 + 1];
            vz[rr] = V_st[e * 3 + 2];
            nd[rr] = idx_t[e];
        }
    }

    // ---- stage A: thread (arow=tid>>2, agg=tid&3) streams 8 x 32B ----
    const int arow = tid >> 2;        // 0..31
    const int agg  = tid & 3;
    const float* abase = forces + (row0 + arow) * D + agg * 8;

    floatx4 f0[8], f1[8];
#pragma unroll
    for (int k0t = 0; k0t < 8; ++k0t) {
        f0[k0t] = __builtin_nontemporal_load((const floatx4*)(abase + k0t * 32));
        f1[k0t] = __builtin_nontemporal_load((const floatx4*)(abase + k0t * 32 + 4));
    }
    const int aslot = ((agg << 4) | (arow & 15)) * 8;
    const int art   = arow >> 4;
#pragma unroll
    for (int k0t = 0; k0t < 8; ++k0t) {
        short8 a;
#pragma unroll
        for (int j = 0; j < 4; ++j) { a[j] = f2bf(f0[k0t][j]); a[4 + j] = f2bf(f1[k0t][j]); }
        *(short8*)&Albs[(k0t * 2 + art) * 512 + aslot] = a;
    }
    __syncthreads();   // the only barrier

    // ---- MFMA: wave tile 16 rows x 256 cols = 16 col-frags ----
    floatx4 acc[16];
#pragma unroll
    for (int nc = 0; nc < 16; ++nc)
        acc[nc] = (floatx4){0.f, 0.f, 0.f, 0.f};

#pragma unroll
    for (int k0t = 0; k0t < 8; ++k0t) {
        short8 af = *(const short8*)&Albs[(k0t * 2 + wm) * 512 + lane * 8];
#pragma unroll
        for (int nc = 0; nc < 16; ++nc) {
            short8 bf = *(const short8*)(W1F + (long)((k0t * 16 + nc) * 64 + lane) * 8);
            acc[nc] = __builtin_amdgcn_mfma_f32_16x16x32_bf16(af, bf, acc[nc], 0, 0, 0);
        }
    }

    // ---- epilogue: silu(z+b1) dot W2 over all 256 cols (b1/W2 L1-hot) ----
    float part[4];   // C/D: col=lane&15, row=(lane>>4)*4+reg (m89)
#pragma unroll
    for (int rr = 0; rr < 4; ++rr) {
        float sv = 0.f;
#pragma unroll
        for (int nc = 0; nc < 16; ++nc) {
            float z = acc[nc][rr] + b1[nc * 16 + l15];
            float h = z / (1.f + __expf(-z));
            sv += h * W2[nc * 16 + l15];
        }
        part[rr] = sv;
    }

#pragma unroll
    for (int off = 1; off < 16; off <<= 1)
#pragma unroll
        for (int rr = 0; rr < 4; ++rr)
            part[rr] += __shfl_xor(part[rr], off, 16);

    // ---- scatter from the owning lanes (row = wm*16 + g*4 + rr) ----
    if (l15 == 0) {
        const float b2v = b2[0];
#pragma unroll
        for (int rr = 0; rr < 4; ++rr) {
            float sv = part[rr] + b2v;
            atomicAdd(&out[(long)nd[rr] * 3 + 0], sv * vx[rr]);
            atomicAdd(&out[(long)nd[rr] * 3 + 1], sv * vy[rr]);
            atomicAdd(&out[(long)nd[rr] * 3 + 2], sv * vz[rr]);
        }
    }
}

extern "C" void kernel_launch(void* const* d_in, const int* in_sizes, int n_in,
                              void* d_out, int out_size, void* d_ws, size_t ws_size,
                              hipStream_t stream) {
    const float* forces = (const float*)d_in[0];
    const float* V_st   = (const float*)d_in[1];
    const float* W1     = (const float*)d_in[2];
    const float* b1     = (const float*)d_in[3];
    const float* W2     = (const float*)d_in[4];
    const float* b2     = (const float*)d_in[5];
    const int*   idx    = (const int*)d_in[6];
    const int E = in_sizes[6];

    u16* W1F = (u16*)d_ws;  // 256*256*2 = 131072 B

    prep_kernel<<<D + 128, 256, 0, stream>>>(W1, W1F, (float*)d_out, out_size);
    const int grid = E / BM;
    head_kernel<<<grid, NT, 0, stream>>>(forces, V_st, W1F, b1, W2, b2, idx,
                                         (float*)d_out, E);
}

// Round 14
// 316.003 us; speedup vs baseline: 1.2301x; 1.2301x over previous
//
#include <hip/hip_runtime.h>
#include <hip/hip_bf16.h>

typedef __attribute__((ext_vector_type(8))) short short8;
typedef __attribute__((ext_vector_type(4))) float floatx4;
typedef unsigned short u16;

#define D 256
#define BM 64
#define NT 256

__device__ __forceinline__ short f2bf(float f) {
    return __builtin_bit_cast(short, __float2bfloat16(f));
}

// prep: blocks [0,256): W1 fp32 [k][n] -> W1F bf16 MFMA-fragment-major:
// W1F[((k0t*16+nt)*64+lane)*8+j] = W1[k0t*32+(lane>>4)*8+j][nt*16+(lane&15)]
//       blocks [256,384): zero d_out.
__global__ void prep_kernel(const float* __restrict__ W1, u16* __restrict__ W1F,
                            float* __restrict__ out, int outn) {
    const int b = blockIdx.x;
    if (b < D) {
        const int k = b, n = threadIdx.x;
        const int k0t = k >> 5, g = (k >> 3) & 3, j = k & 7;
        const int nt = n >> 4, l15 = n & 15;
        W1F[(long)((((k0t << 4) + nt) << 6) + (g << 4) + l15) * 8 + j] = (u16)f2bf(W1[k * D + n]);
    } else {
        int i = (b - D) * 256 + threadIdx.x;
        const int stride = (gridDim.x - D) * 256;
        for (; i < outn; i += stride) out[i] = 0.f;
    }
}

// R11 geometry (64-edge tile, 4 waves, 32.5 KiB LDS -> 4 blocks/CU) with
// STREAMING staging (load->cvt->write per 32B chunk; no register burst-hold,
// no spills). A fragment-major in LDS; B per k-step from L2-resident W1F.
__launch_bounds__(NT, 4)
__global__ void head_kernel(const float* __restrict__ forces,
                            const float* __restrict__ V_st,
                            const u16*   __restrict__ W1F,
                            const float* __restrict__ b1,
                            const float* __restrict__ W2,
                            const float* __restrict__ b2,
                            const int*   __restrict__ idx_t,
                            float* __restrict__ out,
                            int E) {
    // frag f = k0t*4 + (row>>4); in-frag slot ((g<<4)|(row&15))*8 + j shorts
    __shared__ u16 Albs[32 * 512];    // 32 KiB
    __shared__ float s_red[2][BM];    // 512 B

    const int tid  = threadIdx.x;
    const int lane = tid & 63;
    const int w    = tid >> 6;        // 0..3
    const int wm   = w >> 1;          // row half 0..1
    const int wn   = w & 1;           // col half 0..1
    const int l15  = lane & 15;
    const int g    = lane >> 4;       // 0..3

    const long row0 = (long)blockIdx.x * BM;   // E%64==0: no tail

    // ---- scatter-operand prefetch (in flight across the whole block) ----
    float vx = 0.f, vy = 0.f, vz = 0.f;
    int node = -1;
    if (tid < BM) {
        long e = row0 + tid;
        vx = V_st[e * 3 + 0]; vy = V_st[e * 3 + 1]; vz = V_st[e * 3 + 2];
        node = idx_t[e];
    }

    // ---- stage A, streaming: chunk c = it*NT+tid covers (row=c>>5, ch=c&31) ----
#pragma unroll
    for (int it = 0; it < 8; ++it) {
        int c   = it * NT + tid;      // 0..2047
        int row = c >> 5;             // 0..63
        int ch  = c & 31;             // 32B chunk within row
        int k0t = ch >> 2, gg = ch & 3;
        const float* src = forces + (row0 + row) * D + ch * 8;
        floatx4 f0 = __builtin_nontemporal_load((const floatx4*)src);
        floatx4 f1 = __builtin_nontemporal_load((const floatx4*)(src + 4));
        short8 a;
#pragma unroll
        for (int j = 0; j < 4; ++j) { a[j] = f2bf(f0[j]); a[4 + j] = f2bf(f1[j]); }
        *(short8*)&Albs[(k0t * 4 + (row >> 4)) * 512 + (((gg << 4) | (row & 15)) * 8)] = a;
    }
    __syncthreads();

    // ---- MFMA: wave tile 32 rows x 128 cols = 2 mr x 8 nc fragments ----
    floatx4 acc[2][8];
#pragma unroll
    for (int mr = 0; mr < 2; ++mr)
#pragma unroll
        for (int nc = 0; nc < 8; ++nc)
            acc[mr][nc] = (floatx4){0.f, 0.f, 0.f, 0.f};

#pragma unroll
    for (int k0t = 0; k0t < 8; ++k0t) {
        short8 bf[8], af[2];
#pragma unroll
        for (int nc = 0; nc < 8; ++nc)
            bf[nc] = *(const short8*)(W1F + (long)((k0t * 16 + wn * 8 + nc) * 64 + lane) * 8);
#pragma unroll
        for (int mr = 0; mr < 2; ++mr)
            af[mr] = *(const short8*)&Albs[(k0t * 4 + wm * 2 + mr) * 512 + lane * 8];
#pragma unroll
        for (int mr = 0; mr < 2; ++mr)
#pragma unroll
            for (int nc = 0; nc < 8; ++nc)
                acc[mr][nc] = __builtin_amdgcn_mfma_f32_16x16x32_bf16(
                    af[mr], bf[nc], acc[mr][nc], 0, 0, 0);
    }

    // ---- epilogue: silu(z+b1) dot W2 over this wave's 128 cols ----
    float b1v[8], w2v[8];
#pragma unroll
    for (int nc = 0; nc < 8; ++nc) {
        int n = wn * 128 + nc * 16 + l15;
        b1v[nc] = b1[n];
        w2v[nc] = W2[n];
    }
    float part[2][4];  // C/D: col=lane&15, row=(lane>>4)*4+reg (m89)
#pragma unroll
    for (int mr = 0; mr < 2; ++mr)
#pragma unroll
        for (int rr = 0; rr < 4; ++rr) {
            float sv = 0.f;
#pragma unroll
            for (int nc = 0; nc < 8; ++nc) {
                float z = acc[mr][nc][rr] + b1v[nc];
                float h = z / (1.f + __expf(-z));
                sv += h * w2v[nc];
            }
            part[mr][rr] = sv;
        }

#pragma unroll
    for (int off = 1; off < 16; off <<= 1)
#pragma unroll
        for (int mr = 0; mr < 2; ++mr)
#pragma unroll
            for (int rr = 0; rr < 4; ++rr)
                part[mr][rr] += __shfl_xor(part[mr][rr], off, 16);

    if (l15 == 0) {
#pragma unroll
        for (int mr = 0; mr < 2; ++mr)
#pragma unroll
            for (int rr = 0; rr < 4; ++rr)
                s_red[wn][wm * 32 + mr * 16 + g * 4 + rr] = part[mr][rr];
    }
    __syncthreads();

    // ---- scalar + scatter (operands already in registers) ----
    if (node >= 0) {
        float sv = s_red[0][tid] + s_red[1][tid] + b2[0];
        atomicAdd(&out[(long)node * 3 + 0], sv * vx);
        atomicAdd(&out[(long)node * 3 + 1], sv * vy);
        atomicAdd(&out[(long)node * 3 + 2], sv * vz);
    }
}

extern "C" void kernel_launch(void* const* d_in, const int* in_sizes, int n_in,
                              void* d_out, int out_size, void* d_ws, size_t ws_size,
                              hipStream_t stream) {
    const float* forces = (const float*)d_in[0];
    const float* V_st   = (const float*)d_in[1];
    const float* W1     = (const float*)d_in[2];
    const float* b1     = (const float*)d_in[3];
    const float* W2     = (const float*)d_in[4];
    const float* b2     = (const float*)d_in[5];
    const int*   idx    = (const int*)d_in[6];
    const int E = in_sizes[6];

    u16* W1F = (u16*)d_ws;  // 256*256*2 = 131072 B

    prep_kernel<<<D + 128, 256, 0, stream>>>(W1, W1F, (float*)d_out, out_size);
    const int grid = E / BM;
    head_kernel<<<grid, NT, 0, stream>>>(forces, V_st, W1F, b1, W2, b2, idx,
                                         (float*)d_out, E);
}

// Round 15
// 291.254 us; speedup vs baseline: 1.3347x; 1.0850x over previous
//
#include <hip/hip_runtime.h>
#include <hip/hip_bf16.h>

typedef __attribute__((ext_vector_type(8))) short short8;
typedef __attribute__((ext_vector_type(4))) float floatx4;
typedef unsigned short u16;

#define D 256
#define BM 32
#define NT 128

__device__ __forceinline__ short f2bf(float f) {
    return __builtin_bit_cast(short, __float2bfloat16(f));
}

// prep: blocks [0,256): W1 fp32 [k][n] -> W1F bf16 MFMA-fragment-major:
// W1F[((k0t*16+nt)*64+lane)*8+j] = W1[k0t*32+(lane>>4)*8+j][nt*16+(lane&15)]
//       blocks [256,384): zero d_out.
__global__ void prep_kernel(const float* __restrict__ W1, u16* __restrict__ W1F,
                            float* __restrict__ out, int outn) {
    const int b = blockIdx.x;
    if (b < D) {
        const int k = b, n = threadIdx.x;
        const int k0t = k >> 5, g = (k >> 3) & 3, j = k & 7;
        const int nt = n >> 4, l15 = n & 15;
        W1F[(long)((((k0t << 4) + nt) << 6) + (g << 4) + l15) * 8 + j] = (u16)f2bf(W1[k * D + n]);
    } else {
        int i = (b - D) * 256 + threadIdx.x;
        const int stride = (gridDim.x - D) * 256;
        for (; i < outn; i += stride) out[i] = 0.f;
    }
}

struct R8 { floatx4 f0, f1; };

// 8-blocks/CU head: 32-edge tile, 2 waves, 16.4 KiB LDS, burst staging.
// Wave tile = 32 rows x 128 cols (wn col-half): acc 64 VGPR, bf[8] inner
// loop, 4 KB/row B-traffic -- R11's proven per-wave structure, half the
// block granularity, 2x the independent blocks per CU.
__launch_bounds__(NT, 4)
__global__ void head_kernel(const float* __restrict__ forces,
                            const float* __restrict__ V_st,
                            const u16*   __restrict__ W1F,
                            const float* __restrict__ b1,
                            const float* __restrict__ W2,
                            const float* __restrict__ b2,
                            const int*   __restrict__ idx_t,
                            float* __restrict__ out,
                            int E) {
    // A frag f = k0t*2 + (row>>4); in-frag slot ((g<<4)|(row&15))*8 + j shorts
    __shared__ u16 Albs[16 * 512];    // 16 KiB
    __shared__ float s_red[2][BM];    // 256 B

    const int tid  = threadIdx.x;
    const int lane = tid & 63;
    const int wn   = tid >> 6;        // 0..1: col half
    const int l15  = lane & 15;
    const int g    = lane >> 4;       // 0..3

    const long row0 = (long)blockIdx.x * BM;   // E%32==0: no tail

    // ---- scatter-operand prefetch (in flight across the whole block) ----
    float vx = 0.f, vy = 0.f, vz = 0.f;
    int node = -1;
    if (tid < BM) {
        long e = row0 + tid;
        vx = V_st[e * 3 + 0]; vy = V_st[e * 3 + 1]; vz = V_st[e * 3 + 2];
        node = idx_t[e];
    }

    // ---- stage A: burst 16 loads (thread = arow=tid>>2, agg=tid&3) ----
    const int arow = tid >> 2;        // 0..31
    const int agg  = tid & 3;
    const float* abase = forces + (row0 + arow) * D + agg * 8;

    R8 r[8];
#pragma unroll
    for (int k0t = 0; k0t < 8; ++k0t) {
        r[k0t].f0 = *(const floatx4*)(abase + k0t * 32);
        r[k0t].f1 = *(const floatx4*)(abase + k0t * 32 + 4);
    }
    const int aslot = ((agg << 4) | (arow & 15)) * 8;
    const int art   = arow >> 4;
#pragma unroll
    for (int k0t = 0; k0t < 8; ++k0t) {
        short8 a;
#pragma unroll
        for (int j = 0; j < 4; ++j) { a[j] = f2bf(r[k0t].f0[j]); a[4 + j] = f2bf(r[k0t].f1[j]); }
        *(short8*)&Albs[(k0t * 2 + art) * 512 + aslot] = a;
    }
    __syncthreads();

    // ---- MFMA: wave tile 32 rows x 128 cols = 2 mr x 8 nc fragments ----
    floatx4 acc[2][8];
#pragma unroll
    for (int mr = 0; mr < 2; ++mr)
#pragma unroll
        for (int nc = 0; nc < 8; ++nc)
            acc[mr][nc] = (floatx4){0.f, 0.f, 0.f, 0.f};

#pragma unroll
    for (int k0t = 0; k0t < 8; ++k0t) {
        short8 bf[8], af[2];
#pragma unroll
        for (int nc = 0; nc < 8; ++nc)
            bf[nc] = *(const short8*)(W1F + (long)((k0t * 16 + wn * 8 + nc) * 64 + lane) * 8);
#pragma unroll
        for (int mr = 0; mr < 2; ++mr)
            af[mr] = *(const short8*)&Albs[(k0t * 2 + mr) * 512 + lane * 8];
#pragma unroll
        for (int mr = 0; mr < 2; ++mr)
#pragma unroll
            for (int nc = 0; nc < 8; ++nc)
                acc[mr][nc] = __builtin_amdgcn_mfma_f32_16x16x32_bf16(
                    af[mr], bf[nc], acc[mr][nc], 0, 0, 0);
    }

    // ---- epilogue: silu(z+b1) dot W2 over this wave's 128 cols ----
    float b1v[8], w2v[8];
#pragma unroll
    for (int nc = 0; nc < 8; ++nc) {
        int n = wn * 128 + nc * 16 + l15;
        b1v[nc] = b1[n];
        w2v[nc] = W2[n];
    }
    float part[2][4];  // C/D: col=lane&15, row=(lane>>4)*4+reg (m89)
#pragma unroll
    for (int mr = 0; mr < 2; ++mr)
#pragma unroll
        for (int rr = 0; rr < 4; ++rr) {
            float sv = 0.f;
#pragma unroll
            for (int nc = 0; nc < 8; ++nc) {
                float z = acc[mr][nc][rr] + b1v[nc];
                float h = z / (1.f + __expf(-z));
                sv += h * w2v[nc];
            }
            part[mr][rr] = sv;
        }

#pragma unroll
    for (int off = 1; off < 16; off <<= 1)
#pragma unroll
        for (int mr = 0; mr < 2; ++mr)
#pragma unroll
            for (int rr = 0; rr < 4; ++rr)
                part[mr][rr] += __shfl_xor(part[mr][rr], off, 16);

    if (l15 == 0) {
#pragma unroll
        for (int mr = 0; mr < 2; ++mr)
#pragma unroll
            for (int rr = 0; rr < 4; ++rr)
                s_red[wn][mr * 16 + g * 4 + rr] = part[mr][rr];
    }
    __syncthreads();

    // ---- scalar + scatter (operands already in registers) ----
    if (node >= 0) {
        float sv = s_red[0][tid] + s_red[1][tid] + b2[0];
        atomicAdd(&out[(long)node * 3 + 0], sv * vx);
        atomicAdd(&out[(long)node * 3 + 1], sv * vy);
        atomicAdd(&out[(long)node * 3 + 2], sv * vz);
    }
}

extern "C" void kernel_launch(void* const* d_in, const int* in_sizes, int n_in,
                              void* d_out, int out_size, void* d_ws, size_t ws_size,
                              hipStream_t stream) {
    const float* forces = (const float*)d_in[0];
    const float* V_st   = (const float*)d_in[1];
    const float* W1     = (const float*)d_in[2];
    const float* b1     = (const float*)d_in[3];
    const float* W2     = (const float*)d_in[4];
    const float* b2     = (const float*)d_in[5];
    const int*   idx    = (const int*)d_in[6];
    const int E = in_sizes[6];

    u16* W1F = (u16*)d_ws;  // 256*256*2 = 131072 B

    prep_kernel<<<D + 128, 256, 0, stream>>>(W1, W1F, (float*)d_out, out_size);
    const int grid = E / BM;
    head_kernel<<<grid, NT, 0, stream>>>(forces, V_st, W1F, b1, W2, b2, idx,
                                         (float*)d_out, E);
}